// Round 20
// baseline (119.001 us; speedup 1.0000x reference)
//
#include <hip/hip_runtime.h>
#include <hip/hip_bf16.h>

// MVAS: multi-view routed window attention.
// cv: (1,128,128,256) f32   mv: (1,4,128,128,256) f32   out: (1,128,128,256) f32
// 64 windows (8x8) of 16x16 px; 8 heads x 32ch; route top-4 of 256 (4 views x 64 win).

typedef __attribute__((ext_vector_type(4))) float f32x4;
typedef __attribute__((ext_vector_type(8))) short s16x8;
typedef __attribute__((ext_vector_type(2))) unsigned u32x2;
typedef __attribute__((ext_vector_type(4))) unsigned u32x4;

#define SCALE 0.0625f                      // 256^-0.5
#define LOG2E 1.44269504088896340736f
#define KV4S 144                           // padded kv4-group stride (r17): V u16 reads conflict-free

__device__ inline unsigned cvt_pk_bf16(float lo, float hi) {
  unsigned r;
  asm("v_cvt_pk_bf16_f32 %0, %1, %2" : "=v"(r) : "v"(lo), "v"(hi));
  return r;
}
// Compiler-visible RNA bf16 pack (round-half-away): 3 VALU ops/pair vs RNE's 5.
// P is strictly positive/bounded; RNA==RNE except exact ties (1 ulp, ~2^-16
// probability) — r10 ran this exact pack with identical absmax 1.95e-3.
// Compiler-visible => safe as a direct MFMA operand producer (r7 lesson).
__device__ inline unsigned pk_bf16_rna(float lo, float hi) {
  unsigned a = __float_as_uint(lo) + 0x8000u;
  unsigned b = __float_as_uint(hi) + 0x8000u;
  return __builtin_amdgcn_perm(b, a, 0x07060302u);  // {b[3],b[2],a[3],a[2]}
}
#if __has_builtin(__builtin_amdgcn_exp2f)
#define EXP2(x) __builtin_amdgcn_exp2f(x)
#else
#define EXP2(x) exp2f(x)
#endif

// ---------------- kernel 1: window means (vectorized f32x4) ----------------
__global__ __launch_bounds__(256) void k_means(const float* __restrict__ cv,
                                               const float* __restrict__ mv,
                                               float* __restrict__ qwin,
                                               float* __restrict__ kwin) {
  __shared__ f32x4 sm[8][32];
  int wi = blockIdx.x >> 1, half = blockIdx.x & 1;
  int c4 = threadIdx.x & 31, pq = threadIdx.x >> 5;
  const float* base;
  float* dst;
  if (wi < 64) {
    base = cv + ((size_t)((wi >> 3) * 16) * 128 + (wi & 7) * 16) * 256;
    dst = qwin + wi * 256;
  } else {
    int r = wi - 64;
    base = mv + (size_t)(r >> 6) * (128 * 128 * 256)
         + ((size_t)(((r >> 3) & 7) * 16) * 128 + (r & 7) * 16) * 256;
    dst = kwin + r * 256;
  }
  base += half * 128 + c4 * 4;
  f32x4 acc = {0.f, 0.f, 0.f, 0.f};
#pragma unroll 4
  for (int k = 0; k < 32; ++k) {
    int px = pq * 32 + k;
    f32x4 d = *reinterpret_cast<const f32x4*>(base + ((px >> 4) * 128 + (px & 15)) * 256);
    acc += d;
  }
  sm[pq][c4] = acc;
  __syncthreads();
  if (pq == 0) {
    f32x4 s = sm[0][c4];
#pragma unroll
    for (int j = 1; j < 8; ++j) s += sm[j][c4];
    s *= (1.f / 256.f);
    *reinterpret_cast<f32x4*>(dst + half * 128 + c4 * 4) = s;
  }
}

// ---------------- kernel 2: routing logits + top-4 ----------------
__global__ __launch_bounds__(1024) void k_route(const float* __restrict__ qwin,
                                                const float* __restrict__ kwin,
                                                int* __restrict__ ridx) {
  __shared__ float qrow[256];
  __shared__ float part[4][256];
  __shared__ float sv[256];
  __shared__ float wbv[4];
  __shared__ int wbi[4];
  int p = blockIdx.x, t = threadIdx.x;
  int r = t & 255, cq = t >> 8;
  if (t < 256) qrow[t] = qwin[p * 256 + t] * SCALE;
  __syncthreads();
  const f32x4* kr = reinterpret_cast<const f32x4*>(kwin + r * 256 + cq * 64);
  const float* qr = qrow + cq * 64;
  float dot = 0.f;
#pragma unroll
  for (int i = 0; i < 16; ++i) {
    f32x4 kv = kr[i];
    dot += qr[i * 4 + 0] * kv[0] + qr[i * 4 + 1] * kv[1]
         + qr[i * 4 + 2] * kv[2] + qr[i * 4 + 3] * kv[3];
  }
  part[cq][r] = dot;
  __syncthreads();
  if (t < 256) sv[t] = (part[0][t] + part[1][t]) + (part[2][t] + part[3][t]);
  __syncthreads();
  for (int k = 0; k < 4; ++k) {
    if (t < 256) {
      float v = sv[t];
      int ii = t;
#pragma unroll
      for (int off = 32; off > 0; off >>= 1) {
        float ov = __shfl_down(v, off, 64);
        int oi = __shfl_down(ii, off, 64);
        if (ov > v || (ov == v && oi < ii)) { v = ov; ii = oi; }
      }
      if ((t & 63) == 0) { wbv[t >> 6] = v; wbi[t >> 6] = ii; }
    }
    __syncthreads();
    if (t == 0) {
      float bv = wbv[0]; int bi = wbi[0];
      for (int j = 1; j < 4; ++j)
        if (wbv[j] > bv || (wbv[j] == bv && wbi[j] < bi)) { bv = wbv[j]; bi = wbi[j]; }
      ridx[p * 4 + k] = bi;
      sv[bi] = -3.0e38f;
    }
    __syncthreads();
  }
}

// ---------------- kernel 3: MFMA attention (r18 structure + RNA pack) ----------
// block = (window p, head m): 4 fat waves x 64 q-rows (qt=0..3).
// No-max softmax (logits bounded). kv_lds subtiled [kv4][ch-half][4][16] bf16,
// padded stride KV4S=144 (V u16 reads conflict-free; K b128 at 8-pass minimum).
// In-register P via shared k->kv map f(g,j) = (j>>2)*16 + 4g + (j&3).
// Phase-batched step body (r18, the confirmed win): QK batch -> exp batch ->
// lsum+pack batch -> PV batch. r19's lsum-hoist/unroll2 were negative: reverted.
// r20: RNA pack (3 ops/pair vs RNE 5) — kernel is VALU-issue-bound (exp2 at
// quarter-rate = 256 of ~460 VALU cyc/step); pure op removal now translates
// since r18 removed the serial dep chains.
__global__ __launch_bounds__(256, 2) void k_attn(const float* __restrict__ cv,
                                                 const float* __restrict__ mv,
                                                 const int* __restrict__ ridx,
                                                 float* __restrict__ out) {
  __shared__ __align__(16) short kv_lds[64 * KV4S];   // 18 KB

  const int tid = threadIdx.x;
  const int lane = tid & 63, wv = tid >> 6;
  const int g = lane >> 4, c16 = lane & 15;
  const int p = blockIdx.x >> 3, m = blockIdx.x & 7;
  const int py = p >> 3, px = p & 7;

  const int4 ridx4 = *reinterpret_cast<const int4*>(ridx + p * 4);

  // Q fragments (B-operand of QK^T): lane holds Q[q = qt*16+c16][ch = g*8..g*8+7]
  const float qs = SCALE * LOG2E;
  s16x8 qf[4];
#pragma unroll
  for (int qt = 0; qt < 4; ++qt) {
    const float* qp = cv + ((size_t)((py * 16 + wv * 4 + qt) * 128) + px * 16 + c16) * 256
                         + m * 32 + g * 8;
    f32x4 a = *reinterpret_cast<const f32x4*>(qp);
    f32x4 b = *reinterpret_cast<const f32x4*>(qp + 4);
    union { u32x4 u; s16x8 s; } cu;
    cu.u[0] = cvt_pk_bf16(a[0] * qs, a[1] * qs);
    cu.u[1] = cvt_pk_bf16(a[2] * qs, a[3] * qs);
    cu.u[2] = cvt_pk_bf16(b[0] * qs, b[1] * qs);
    cu.u[3] = cvt_pk_bf16(b[2] * qs, b[3] * qs);
    qf[qt] = cu.s;
  }

  f32x4 accO[4][2];
  float lsum[4];
#pragma unroll
  for (int qt = 0; qt < 4; ++qt) {
    lsum[qt] = 0.f;
    accO[qt][0] = f32x4{0.f, 0.f, 0.f, 0.f};
    accO[qt][1] = f32x4{0.f, 0.f, 0.f, 0.f};
  }
  const f32x4 zf = {0.f, 0.f, 0.f, 0.f};

  for (int w = 0; w < 4; ++w) {
    if (w) __syncthreads();  // all reads of window w-1 done before overwrite
    {
      int r = (&ridx4.x)[w];
      const float* srcb = mv + (size_t)(r >> 6) * (128 * 128 * 256)
                        + ((size_t)(((r >> 3) & 7) * 16) * 128 + (r & 7) * 16) * 256 + m * 32;
#pragma unroll
      for (int i = 0; i < 8; ++i) {
        int u = i * 256 + tid;
        int pxl = u >> 3, quad = u & 7;
        f32x4 d = *reinterpret_cast<const f32x4*>(
            srcb + ((pxl >> 4) * 128 + (pxl & 15)) * 256 + quad * 4);
        u32x2 pk;
        pk[0] = cvt_pk_bf16(d[0], d[1]);
        pk[1] = cvt_pk_bf16(d[2], d[3]);
        // subtiled addr: [pxl>>2][quad>>2][pxl&3][(quad&3)*4], padded group stride
        int off = (pxl >> 2) * KV4S + (quad >> 2) * 64 + (pxl & 3) * 16 + (quad & 3) * 4;
        *reinterpret_cast<u32x2*>(&kv_lds[off]) = pk;
      }
    }
    __syncthreads();

    for (int s = 0; s < 8; ++s) {
      // ---- K fragments (b128): A[i=c16][k=g*8+j] = K[krow][ch] ----
      int kr0 = s * 32 + c16;          // kt = 0 (kv rows 0-15 of block)
      int kr1 = kr0 + 16;              // kt = 1 (rows 16-31)
      const s16x8 kf0 = *reinterpret_cast<const s16x8*>(
          &kv_lds[(kr0 >> 2) * KV4S + (g >> 1) * 64 + (kr0 & 3) * 16 + (g & 1) * 8]);
      const s16x8 kf1 = *reinterpret_cast<const s16x8*>(
          &kv_lds[(kr1 >> 2) * KV4S + (g >> 1) * 64 + (kr1 & 3) * 16 + (g & 1) * 8]);
      // ---- V A-fragments (scalar u16, conflict-free) with k->kv map f(g,j) ----
      s16x8 V0, V1;
#pragma unroll
      for (int j = 0; j < 8; ++j) {
        int a = (s * 8 + (j >> 2) * 4 + g) * KV4S + (j & 3) * 16 + c16;
        V0[j] = kv_lds[a];
        V1[j] = kv_lds[a + 64];
      }
      // ---- batch 1: all 8 QK MFMAs (independent -> pipelined) ----
      f32x4 sx[4], sy[4];
#pragma unroll
      for (int qt = 0; qt < 4; ++qt) {
        sx[qt] = __builtin_amdgcn_mfma_f32_16x16x32_bf16(kf0, qf[qt], zf, 0, 0, 0);
        sy[qt] = __builtin_amdgcn_mfma_f32_16x16x32_bf16(kf1, qf[qt], zf, 0, 0, 0);
      }
      // ---- batch 2: all 32 exps (trans pipe pipelines) ----
      float ex[4][8];
#pragma unroll
      for (int qt = 0; qt < 4; ++qt) {
        ex[qt][0] = EXP2(sx[qt][0]); ex[qt][1] = EXP2(sx[qt][1]);
        ex[qt][2] = EXP2(sx[qt][2]); ex[qt][3] = EXP2(sx[qt][3]);
        ex[qt][4] = EXP2(sy[qt][0]); ex[qt][5] = EXP2(sy[qt][1]);
        ex[qt][6] = EXP2(sy[qt][2]); ex[qt][7] = EXP2(sy[qt][3]);
      }
      // ---- batch 3: lsum + packs (independent VALU) ----
      union { u32x4 u; s16x8 s; } pb[4];
#pragma unroll
      for (int qt = 0; qt < 4; ++qt) {
        lsum[qt] += ((ex[qt][0] + ex[qt][1]) + (ex[qt][2] + ex[qt][3]))
                  + ((ex[qt][4] + ex[qt][5]) + (ex[qt][6] + ex[qt][7]));
        pb[qt].u[0] = pk_bf16_rna(ex[qt][0], ex[qt][1]);   // j=0,1: kv 4g,4g+1
        pb[qt].u[1] = pk_bf16_rna(ex[qt][2], ex[qt][3]);   // j=2,3: kv 4g+2,4g+3
        pb[qt].u[2] = pk_bf16_rna(ex[qt][4], ex[qt][5]);   // j=4,5: kv 16+4g..
        pb[qt].u[3] = pk_bf16_rna(ex[qt][6], ex[qt][7]);   // j=6,7: kv 16+4g+2..
      }
      // ---- batch 4: all 8 PV MFMAs (independent accumulators) ----
#pragma unroll
      for (int qt = 0; qt < 4; ++qt) {
        accO[qt][0] = __builtin_amdgcn_mfma_f32_16x16x32_bf16(V0, pb[qt].s, accO[qt][0], 0, 0, 0);
        accO[qt][1] = __builtin_amdgcn_mfma_f32_16x16x32_bf16(V1, pb[qt].s, accO[qt][1], 0, 0, 0);
      }
    }
  }

  // ---- epilogue: reduce l across the 4 lane-groups, normalize, store ----
#pragma unroll
  for (int qt = 0; qt < 4; ++qt) {
    float l = lsum[qt];
    l += __shfl_xor(l, 16, 64);
    l += __shfl_xor(l, 32, 64);
    float rl = 1.f / l;
#pragma unroll
    for (int mt = 0; mt < 2; ++mt) {
      f32x4 o = accO[qt][mt];
      o[0] *= rl; o[1] *= rl; o[2] *= rl; o[3] *= rl;
      float* op = out + ((size_t)((py * 16 + wv * 4 + qt) * 128) + px * 16 + c16) * 256
                      + m * 32 + mt * 16 + g * 4;
      *reinterpret_cast<f32x4*>(op) = o;
    }
  }
}

extern "C" void kernel_launch(void* const* d_in, const int* in_sizes, int n_in,
                              void* d_out, int out_size, void* d_ws, size_t ws_size,
                              hipStream_t stream) {
  const float* cv = (const float*)d_in[0];
  const float* mv = (const float*)d_in[1];
  float* out = (float*)d_out;

  float* qwin = (float*)d_ws;                 // 64*256 f32
  float* kwin = qwin + 64 * 256;              // 256*256 f32
  int* ridx = (int*)(kwin + 256 * 256);       // 64*4 i32

  k_means<<<640, 256, 0, stream>>>(cv, mv, qwin, kwin);
  k_route<<<64, 1024, 0, stream>>>(qwin, kwin, ridx);
  k_attn<<<512, 256, 0, stream>>>(cv, mv, ridx, out);
}

// Round 21
// 69.695 us; speedup vs baseline: 1.7074x; 1.7074x over previous
//
#include <hip/hip_runtime.h>
#include <hip/hip_bf16.h>

// MVAS: multi-view routed window attention.
// cv: (1,128,128,256) f32   mv: (1,4,128,128,256) f32   out: (1,128,128,256) f32
// 64 windows (8x8) of 16x16 px; 8 heads x 32ch; route top-4 of 256 (4 views x 64 win).
//
// FINAL (r21 = r18 verbatim, session best 69.94 us):
//  - k_attn: 4 fat waves x 64 q-rows, subtiled kv_lds (KV4S=144 pad), in-register
//    P (shared k->kv map), phase-batched step body, RNE pack, EXP2 builtin.
//  - 12 hot-loop experiments, 1 win (phase-batching). RNA pack (r20) spills
//    (perm liveness); lsum-hoist/unroll2 (r19) negative; setprio (r16) negative;
//    tr_read broken twice; manual pipeline spills; occupancy changes no-op.

typedef __attribute__((ext_vector_type(4))) float f32x4;
typedef __attribute__((ext_vector_type(8))) short s16x8;
typedef __attribute__((ext_vector_type(2))) unsigned u32x2;
typedef __attribute__((ext_vector_type(4))) unsigned u32x4;

#define SCALE 0.0625f                      // 256^-0.5
#define LOG2E 1.44269504088896340736f
#define KV4S 144                           // padded kv4-group stride: V u16 reads conflict-free

__device__ inline unsigned cvt_pk_bf16(float lo, float hi) {
  unsigned r;
  asm("v_cvt_pk_bf16_f32 %0, %1, %2" : "=v"(r) : "v"(lo), "v"(hi));
  return r;
}
// Compiler-visible RNE bf16 pack: safe as a direct MFMA operand producer
// (inline-asm defs feeding MFMA reads can miss VALU->MFMA hazard NOPs - r7 NaN).
// Do NOT swap for the perm-based RNA pack: its 2-live-operand form blows
// register liveness in the batched structure (r20: VGPR 128 + 198MB spill).
__device__ inline unsigned pk_bf16_rne(float lo, float hi) {
  unsigned a = __float_as_uint(lo);
  unsigned b = __float_as_uint(hi);
  a += 0x7FFFu + ((a >> 16) & 1u);
  b += 0x7FFFu + ((b >> 16) & 1u);
  return (a >> 16) | (b & 0xFFFF0000u);
}
#if __has_builtin(__builtin_amdgcn_exp2f)
#define EXP2(x) __builtin_amdgcn_exp2f(x)
#else
#define EXP2(x) exp2f(x)
#endif

// ---------------- kernel 1: window means (vectorized f32x4) ----------------
__global__ __launch_bounds__(256) void k_means(const float* __restrict__ cv,
                                               const float* __restrict__ mv,
                                               float* __restrict__ qwin,
                                               float* __restrict__ kwin) {
  __shared__ f32x4 sm[8][32];
  int wi = blockIdx.x >> 1, half = blockIdx.x & 1;
  int c4 = threadIdx.x & 31, pq = threadIdx.x >> 5;
  const float* base;
  float* dst;
  if (wi < 64) {
    base = cv + ((size_t)((wi >> 3) * 16) * 128 + (wi & 7) * 16) * 256;
    dst = qwin + wi * 256;
  } else {
    int r = wi - 64;
    base = mv + (size_t)(r >> 6) * (128 * 128 * 256)
         + ((size_t)(((r >> 3) & 7) * 16) * 128 + (r & 7) * 16) * 256;
    dst = kwin + r * 256;
  }
  base += half * 128 + c4 * 4;
  f32x4 acc = {0.f, 0.f, 0.f, 0.f};
#pragma unroll 4
  for (int k = 0; k < 32; ++k) {
    int px = pq * 32 + k;
    f32x4 d = *reinterpret_cast<const f32x4*>(base + ((px >> 4) * 128 + (px & 15)) * 256);
    acc += d;
  }
  sm[pq][c4] = acc;
  __syncthreads();
  if (pq == 0) {
    f32x4 s = sm[0][c4];
#pragma unroll
    for (int j = 1; j < 8; ++j) s += sm[j][c4];
    s *= (1.f / 256.f);
    *reinterpret_cast<f32x4*>(dst + half * 128 + c4 * 4) = s;
  }
}

// ---------------- kernel 2: routing logits + top-4 ----------------
__global__ __launch_bounds__(1024) void k_route(const float* __restrict__ qwin,
                                                const float* __restrict__ kwin,
                                                int* __restrict__ ridx) {
  __shared__ float qrow[256];
  __shared__ float part[4][256];
  __shared__ float sv[256];
  __shared__ float wbv[4];
  __shared__ int wbi[4];
  int p = blockIdx.x, t = threadIdx.x;
  int r = t & 255, cq = t >> 8;
  if (t < 256) qrow[t] = qwin[p * 256 + t] * SCALE;
  __syncthreads();
  const f32x4* kr = reinterpret_cast<const f32x4*>(kwin + r * 256 + cq * 64);
  const float* qr = qrow + cq * 64;
  float dot = 0.f;
#pragma unroll
  for (int i = 0; i < 16; ++i) {
    f32x4 kv = kr[i];
    dot += qr[i * 4 + 0] * kv[0] + qr[i * 4 + 1] * kv[1]
         + qr[i * 4 + 2] * kv[2] + qr[i * 4 + 3] * kv[3];
  }
  part[cq][r] = dot;
  __syncthreads();
  if (t < 256) sv[t] = (part[0][t] + part[1][t]) + (part[2][t] + part[3][t]);
  __syncthreads();
  for (int k = 0; k < 4; ++k) {
    if (t < 256) {
      float v = sv[t];
      int ii = t;
#pragma unroll
      for (int off = 32; off > 0; off >>= 1) {
        float ov = __shfl_down(v, off, 64);
        int oi = __shfl_down(ii, off, 64);
        if (ov > v || (ov == v && oi < ii)) { v = ov; ii = oi; }
      }
      if ((t & 63) == 0) { wbv[t >> 6] = v; wbi[t >> 6] = ii; }
    }
    __syncthreads();
    if (t == 0) {
      float bv = wbv[0]; int bi = wbi[0];
      for (int j = 1; j < 4; ++j)
        if (wbv[j] > bv || (wbv[j] == bv && wbi[j] < bi)) { bv = wbv[j]; bi = wbi[j]; }
      ridx[p * 4 + k] = bi;
      sv[bi] = -3.0e38f;
    }
    __syncthreads();
  }
}

// ---------------- kernel 3: MFMA attention (r18 final) ----------
// block = (window p, head m): 4 fat waves x 64 q-rows (qt=0..3).
// No-max softmax (logits bounded). kv_lds subtiled [kv4][ch-half][4][16] bf16,
// padded stride KV4S=144 (V u16 reads conflict-free; K b128 at 8-pass minimum).
// In-register P via shared k->kv map f(g,j) = (j>>2)*16 + 4g + (j&3).
// Phase-batched step body: QK batch -> exp batch -> lsum+pack batch -> PV batch.
__global__ __launch_bounds__(256, 2) void k_attn(const float* __restrict__ cv,
                                                 const float* __restrict__ mv,
                                                 const int* __restrict__ ridx,
                                                 float* __restrict__ out) {
  __shared__ __align__(16) short kv_lds[64 * KV4S];   // 18 KB

  const int tid = threadIdx.x;
  const int lane = tid & 63, wv = tid >> 6;
  const int g = lane >> 4, c16 = lane & 15;
  const int p = blockIdx.x >> 3, m = blockIdx.x & 7;
  const int py = p >> 3, px = p & 7;

  const int4 ridx4 = *reinterpret_cast<const int4*>(ridx + p * 4);

  // Q fragments (B-operand of QK^T): lane holds Q[q = qt*16+c16][ch = g*8..g*8+7]
  const float qs = SCALE * LOG2E;
  s16x8 qf[4];
#pragma unroll
  for (int qt = 0; qt < 4; ++qt) {
    const float* qp = cv + ((size_t)((py * 16 + wv * 4 + qt) * 128) + px * 16 + c16) * 256
                         + m * 32 + g * 8;
    f32x4 a = *reinterpret_cast<const f32x4*>(qp);
    f32x4 b = *reinterpret_cast<const f32x4*>(qp + 4);
    union { u32x4 u; s16x8 s; } cu;
    cu.u[0] = cvt_pk_bf16(a[0] * qs, a[1] * qs);
    cu.u[1] = cvt_pk_bf16(a[2] * qs, a[3] * qs);
    cu.u[2] = cvt_pk_bf16(b[0] * qs, b[1] * qs);
    cu.u[3] = cvt_pk_bf16(b[2] * qs, b[3] * qs);
    qf[qt] = cu.s;
  }

  f32x4 accO[4][2];
  float lsum[4];
#pragma unroll
  for (int qt = 0; qt < 4; ++qt) {
    lsum[qt] = 0.f;
    accO[qt][0] = f32x4{0.f, 0.f, 0.f, 0.f};
    accO[qt][1] = f32x4{0.f, 0.f, 0.f, 0.f};
  }
  const f32x4 zf = {0.f, 0.f, 0.f, 0.f};

  for (int w = 0; w < 4; ++w) {
    if (w) __syncthreads();  // all reads of window w-1 done before overwrite
    {
      int r = (&ridx4.x)[w];
      const float* srcb = mv + (size_t)(r >> 6) * (128 * 128 * 256)
                        + ((size_t)(((r >> 3) & 7) * 16) * 128 + (r & 7) * 16) * 256 + m * 32;
#pragma unroll
      for (int i = 0; i < 8; ++i) {
        int u = i * 256 + tid;
        int pxl = u >> 3, quad = u & 7;
        f32x4 d = *reinterpret_cast<const f32x4*>(
            srcb + ((pxl >> 4) * 128 + (pxl & 15)) * 256 + quad * 4);
        u32x2 pk;
        pk[0] = cvt_pk_bf16(d[0], d[1]);
        pk[1] = cvt_pk_bf16(d[2], d[3]);
        // subtiled addr: [pxl>>2][quad>>2][pxl&3][(quad&3)*4], padded group stride
        int off = (pxl >> 2) * KV4S + (quad >> 2) * 64 + (pxl & 3) * 16 + (quad & 3) * 4;
        *reinterpret_cast<u32x2*>(&kv_lds[off]) = pk;
      }
    }
    __syncthreads();

    for (int s = 0; s < 8; ++s) {
      // ---- K fragments (b128): A[i=c16][k=g*8+j] = K[krow][ch] ----
      int kr0 = s * 32 + c16;          // kt = 0 (kv rows 0-15 of block)
      int kr1 = kr0 + 16;              // kt = 1 (rows 16-31)
      const s16x8 kf0 = *reinterpret_cast<const s16x8*>(
          &kv_lds[(kr0 >> 2) * KV4S + (g >> 1) * 64 + (kr0 & 3) * 16 + (g & 1) * 8]);
      const s16x8 kf1 = *reinterpret_cast<const s16x8*>(
          &kv_lds[(kr1 >> 2) * KV4S + (g >> 1) * 64 + (kr1 & 3) * 16 + (g & 1) * 8]);
      // ---- V A-fragments (scalar u16, conflict-free) with k->kv map f(g,j) ----
      s16x8 V0, V1;
#pragma unroll
      for (int j = 0; j < 8; ++j) {
        int a = (s * 8 + (j >> 2) * 4 + g) * KV4S + (j & 3) * 16 + c16;
        V0[j] = kv_lds[a];
        V1[j] = kv_lds[a + 64];
      }
      // ---- batch 1: all 8 QK MFMAs (independent -> pipelined) ----
      f32x4 sx[4], sy[4];
#pragma unroll
      for (int qt = 0; qt < 4; ++qt) {
        sx[qt] = __builtin_amdgcn_mfma_f32_16x16x32_bf16(kf0, qf[qt], zf, 0, 0, 0);
        sy[qt] = __builtin_amdgcn_mfma_f32_16x16x32_bf16(kf1, qf[qt], zf, 0, 0, 0);
      }
      // ---- batch 2: all 32 exps (trans pipe pipelines) ----
      float ex[4][8];
#pragma unroll
      for (int qt = 0; qt < 4; ++qt) {
        ex[qt][0] = EXP2(sx[qt][0]); ex[qt][1] = EXP2(sx[qt][1]);
        ex[qt][2] = EXP2(sx[qt][2]); ex[qt][3] = EXP2(sx[qt][3]);
        ex[qt][4] = EXP2(sy[qt][0]); ex[qt][5] = EXP2(sy[qt][1]);
        ex[qt][6] = EXP2(sy[qt][2]); ex[qt][7] = EXP2(sy[qt][3]);
      }
      // ---- batch 3: lsum + packs (independent VALU) ----
      union { u32x4 u; s16x8 s; } pb[4];
#pragma unroll
      for (int qt = 0; qt < 4; ++qt) {
        lsum[qt] += ((ex[qt][0] + ex[qt][1]) + (ex[qt][2] + ex[qt][3]))
                  + ((ex[qt][4] + ex[qt][5]) + (ex[qt][6] + ex[qt][7]));
        pb[qt].u[0] = pk_bf16_rne(ex[qt][0], ex[qt][1]);   // j=0,1: kv 4g,4g+1
        pb[qt].u[1] = pk_bf16_rne(ex[qt][2], ex[qt][3]);   // j=2,3: kv 4g+2,4g+3
        pb[qt].u[2] = pk_bf16_rne(ex[qt][4], ex[qt][5]);   // j=4,5: kv 16+4g..
        pb[qt].u[3] = pk_bf16_rne(ex[qt][6], ex[qt][7]);   // j=6,7: kv 16+4g+2..
      }
      // ---- batch 4: all 8 PV MFMAs (independent accumulators) ----
#pragma unroll
      for (int qt = 0; qt < 4; ++qt) {
        accO[qt][0] = __builtin_amdgcn_mfma_f32_16x16x32_bf16(V0, pb[qt].s, accO[qt][0], 0, 0, 0);
        accO[qt][1] = __builtin_amdgcn_mfma_f32_16x16x32_bf16(V1, pb[qt].s, accO[qt][1], 0, 0, 0);
      }
    }
  }

  // ---- epilogue: reduce l across the 4 lane-groups, normalize, store ----
#pragma unroll
  for (int qt = 0; qt < 4; ++qt) {
    float l = lsum[qt];
    l += __shfl_xor(l, 16, 64);
    l += __shfl_xor(l, 32, 64);
    float rl = 1.f / l;
#pragma unroll
    for (int mt = 0; mt < 2; ++mt) {
      f32x4 o = accO[qt][mt];
      o[0] *= rl; o[1] *= rl; o[2] *= rl; o[3] *= rl;
      float* op = out + ((size_t)((py * 16 + wv * 4 + qt) * 128) + px * 16 + c16) * 256
                      + m * 32 + mt * 16 + g * 4;
      *reinterpret_cast<f32x4*>(op) = o;
    }
  }
}

extern "C" void kernel_launch(void* const* d_in, const int* in_sizes, int n_in,
                              void* d_out, int out_size, void* d_ws, size_t ws_size,
                              hipStream_t stream) {
  const float* cv = (const float*)d_in[0];
  const float* mv = (const float*)d_in[1];
  float* out = (float*)d_out;

  float* qwin = (float*)d_ws;                 // 64*256 f32
  float* kwin = qwin + 64 * 256;              // 256*256 f32
  int* ridx = (int*)(kwin + 256 * 256);       // 64*4 i32

  k_means<<<640, 256, 0, stream>>>(cv, mv, qwin, kwin);
  k_route<<<64, 1024, 0, stream>>>(qwin, kwin, ridx);
  k_attn<<<512, 256, 0, stream>>>(cv, mv, ridx, out);
}